// Round 4
// baseline (343.720 us; speedup 1.0000x reference)
//
#include <hip/hip_runtime.h>
#include <hip/hip_bf16.h>
#include <stdint.h>

#define B_ 32
#define S_ 2048
#define H_ 1024
#define U_ 1024

typedef __attribute__((ext_vector_type(8))) short short8;
typedef __attribute__((ext_vector_type(4))) float f32x4;

#define AS1 __attribute__((address_space(1)))
#define AS3 __attribute__((address_space(3)))
#define FENCE __builtin_amdgcn_sched_barrier(0)
#define VMC(n) asm volatile("s_waitcnt vmcnt(" #n ")" ::: "memory")
#define LGKM0 asm volatile("s_waitcnt lgkmcnt(0)" ::: "memory")

__device__ __forceinline__ unsigned short f2bf(float f) {
  unsigned int u = __float_as_uint(f);
  u += 0x7fffu + ((u >> 16) & 1u);   // RNE
  return (unsigned short)(u >> 16);
}

// ---------- prep 1: W1 [H][U] f32 -> W1T [U][H] bf16 ----------
__global__ void k_transpose_w1(const float* __restrict__ W1, unsigned short* __restrict__ W1T) {
  __shared__ float tile[64][65];
  const int tx = threadIdx.x, ty = threadIdx.y;
  const int u0 = blockIdx.x * 64, h0 = blockIdx.y * 64;
#pragma unroll
  for (int i = 0; i < 16; ++i) {
    int hl = ty + i * 4;
    tile[hl][tx] = W1[(size_t)(h0 + hl) * U_ + (u0 + tx)];
  }
  __syncthreads();
#pragma unroll
  for (int i = 0; i < 16; ++i) {
    int ul = ty + i * 4;
    W1T[(size_t)(u0 + ul) * H_ + (h0 + tx)] = f2bf(tile[tx][ul]);
  }
}

// ---------- prep 2: b1q[b][u] = b1[u] + b2[u] + query[b]@W2 ----------
__global__ void k_b1q(const float* __restrict__ query, const float* __restrict__ W2,
                      const float* __restrict__ b1, const float* __restrict__ b2,
                      float* __restrict__ b1q) {
  const int b = blockIdx.y;
  const int u = blockIdx.x * 256 + threadIdx.x;
  float acc = b1[u] + b2[u];
  const float* q = query + b * H_;
#pragma unroll 8
  for (int h = 0; h < H_; ++h) acc += q[h] * W2[(size_t)h * U_ + u];
  b1q[b * U_ + u] = acc;
}

// ---------- fused GEMM+tanh+V: m201-style 8-phase, 256x256x64, 8 waves ----------
#define BMT 256
#define BNT 256
#define BKT 64
#define NTILE 16   // H_/BKT

// LDS: Abuf 2x[256 rows][8 chunks of 16B] = 64 KB, Bbuf same = 64 KB -> 128 KB.
// Swizzle: logical chunk lc of row r stored at phys chunk lc ^ (r&7)  (involution).
// Per K-tile (4 phases q0..q3): compute quadrant q of tile t from buf d=t&1 while
// staging tile t+1 into d^1:  q0: A-loads(t+1,h1)->regs + B-glds(t+1,h0);
// q1: B-glds(t+1,h1); q2: vmcnt(8), cvt+write A(t+1,h0); q3: vmcnt(4),
// cvt+write A(t+1,h1), issue A-loads(t+2,h0), vmcnt(4).  Never vmcnt(0) in loop.
__global__ __launch_bounds__(512, 2)
void k_fused_score(const float* __restrict__ values, const unsigned short* __restrict__ W1T,
                   const float* __restrict__ b1q, const float* __restrict__ V,
                   float* __restrict__ score_part) {
  __shared__ __align__(16) unsigned char smem[131072];
  unsigned short* Abuf = (unsigned short*)smem;              // [2][256*64]
  unsigned short* Bbuf = (unsigned short*)(smem + 65536);    // [2][256*64]
  float* scorebuf = (float*)smem;                            // alias post-loop

  const int tid = threadIdx.x;
  const int g = blockIdx.x;                 // 1024 blocks = 256 bm x 4 bn
  const int seq = (g & 7) * 128 + (g >> 3); // XCD swizzle (bijective, 1024 = 8*128)
  const int bn = seq & 3;
  const int bm = seq >> 2;

  const int lane = tid & 63, wid = tid >> 6;
  const int wm = wid >> 2, wn = wid & 3;
  const int u0 = bn * BNT;

  // A staging addressing: thread -> (row within half, chunk pair)
  const int arow = tid >> 2;                // 0..127
  const int acp  = (tid & 3) * 2;           // chunk-pair base: 0,2,4,6
  const float* aBase = values + (size_t)(bm * BMT) * H_;

  // fragment addresses (shorts), swizzled
  const int l15 = lane & 15, l16 = lane >> 4, l7 = lane & 7;
  const int pA0 = (wm * 128 + l15) * 64 + ((0 + l16) ^ l7) * 8;   // kk=0
  const int pA1 = (wm * 128 + l15) * 64 + ((4 + l16) ^ l7) * 8;   // kk=1
  const int pB0 = (wn * 64 + l15) * 64 + ((0 + l16) ^ l7) * 8;
  const int pB1 = (wn * 64 + l15) * 64 + ((4 + l16) ^ l7) * 8;

  f32x4 acc[8][4];
#pragma unroll
  for (int mf = 0; mf < 8; ++mf)
#pragma unroll
    for (int nf = 0; nf < 4; ++nf) acc[mf][nf] = (f32x4){0.f, 0.f, 0.f, 0.f};

  float4 ar0[4], ar1[4];
  short8 af[4], bfv[8];

#define ISSUE_A(reg, tt, h) { \
    const float4* ap_ = (const float4*)(aBase + (size_t)((h) * 128 + arow) * H_ + (tt) * 64 + acp * 8); \
    reg[0] = ap_[0]; reg[1] = ap_[1]; reg[2] = ap_[2]; reg[3] = ap_[3]; }

#define ISSUE_B(tt, dd, h) { \
    _Pragma("unroll") \
    for (int j_ = 0; j_ < 2; ++j_) { \
      const int pbase_ = (h) * 1024 + (wid * 2 + j_) * 64; \
      const int p_ = pbase_ + lane; \
      const int nr_ = p_ >> 3; \
      const int lc_ = (p_ & 7) ^ (nr_ & 7); \
      const unsigned short* src_ = W1T + (size_t)(u0 + nr_) * H_ + (tt) * 64 + lc_ * 8; \
      __builtin_amdgcn_global_load_lds((const AS1 void*)src_, (AS3 void*)&Bbuf[(dd) * 16384 + pbase_ * 8], 16, 0, 0); } }

#define WRITE_A(reg, dd, h) { \
    short8 w0_, w1_; \
    w0_[0]=f2bf(reg[0].x); w0_[1]=f2bf(reg[0].y); w0_[2]=f2bf(reg[0].z); w0_[3]=f2bf(reg[0].w); \
    w0_[4]=f2bf(reg[1].x); w0_[5]=f2bf(reg[1].y); w0_[6]=f2bf(reg[1].z); w0_[7]=f2bf(reg[1].w); \
    w1_[0]=f2bf(reg[2].x); w1_[1]=f2bf(reg[2].y); w1_[2]=f2bf(reg[2].z); w1_[3]=f2bf(reg[2].w); \
    w1_[4]=f2bf(reg[3].x); w1_[5]=f2bf(reg[3].y); w1_[6]=f2bf(reg[3].z); w1_[7]=f2bf(reg[3].w); \
    const int rl_ = (h) * 128 + arow; \
    *(short8*)&Abuf[(dd) * 16384 + rl_ * 64 + ((acp ^ (rl_ & 7)) << 3)] = w0_; \
    *(short8*)&Abuf[(dd) * 16384 + rl_ * 64 + (((acp + 1) ^ (rl_ & 7)) << 3)] = w1_; }

#define READ_AF(q) \
    af[0] = *(const short8*)&Abuf[dA + pA0 + (2 * (q) + 0) * 1024]; \
    af[1] = *(const short8*)&Abuf[dA + pA1 + (2 * (q) + 0) * 1024]; \
    af[2] = *(const short8*)&Abuf[dA + pA0 + (2 * (q) + 1) * 1024]; \
    af[3] = *(const short8*)&Abuf[dA + pA1 + (2 * (q) + 1) * 1024];

#define PHASE_TAIL(q) \
    FENCE; \
    __builtin_amdgcn_s_barrier(); \
    LGKM0; \
    FENCE; \
    __builtin_amdgcn_s_setprio(1); \
    _Pragma("unroll") \
    for (int nf_ = 0; nf_ < 4; ++nf_) { \
      acc[2*(q)+0][nf_] = __builtin_amdgcn_mfma_f32_16x16x32_bf16(af[0], bfv[2*nf_+0], acc[2*(q)+0][nf_], 0, 0, 0); \
      acc[2*(q)+0][nf_] = __builtin_amdgcn_mfma_f32_16x16x32_bf16(af[1], bfv[2*nf_+1], acc[2*(q)+0][nf_], 0, 0, 0); \
      acc[2*(q)+1][nf_] = __builtin_amdgcn_mfma_f32_16x16x32_bf16(af[2], bfv[2*nf_+0], acc[2*(q)+1][nf_], 0, 0, 0); \
      acc[2*(q)+1][nf_] = __builtin_amdgcn_mfma_f32_16x16x32_bf16(af[3], bfv[2*nf_+1], acc[2*(q)+1][nf_], 0, 0, 0); \
    } \
    __builtin_amdgcn_s_setprio(0); \
    FENCE; \
    __builtin_amdgcn_s_barrier();

  // ---- prologue: stage tile 0 fully; issue A-loads(tile1,h0); leave them in flight ----
  ISSUE_A(ar0, 0, 0);
  ISSUE_A(ar1, 0, 1);
  ISSUE_B(0, 0, 0);
  ISSUE_B(0, 0, 1);
  VMC(8);  WRITE_A(ar0, 0, 0);
  VMC(4);  WRITE_A(ar1, 0, 1);
  FENCE;
  ISSUE_A(ar0, 1, 0);          // tile1 h0 -> regs (in flight across barrier)
  FENCE;
  VMC(4);                      // B(tile0) landed; A(tile1,h0) stays outstanding
  LGKM0;
  __builtin_amdgcn_s_barrier();

  for (int t = 0; t < NTILE; ++t) {
    const int d = t & 1, dn = d ^ 1;
    const int n  = (t + 1 < NTILE) ? (t + 1) : (NTILE - 1);
    const int n2 = (t + 2 < NTILE) ? (t + 2) : (NTILE - 1);
    const int dA = d * 16384;
    const int dB = d * 16384;

    // ---- q0: B-frags(all) + A-frags(q0); issue A(n,h1) + B(n,h0) ----
    READ_AF(0);
    bfv[0] = *(const short8*)&Bbuf[dB + pB0 + 0 * 1024];
    bfv[1] = *(const short8*)&Bbuf[dB + pB1 + 0 * 1024];
    bfv[2] = *(const short8*)&Bbuf[dB + pB0 + 1 * 1024];
    bfv[3] = *(const short8*)&Bbuf[dB + pB1 + 1 * 1024];
    bfv[4] = *(const short8*)&Bbuf[dB + pB0 + 2 * 1024];
    bfv[5] = *(const short8*)&Bbuf[dB + pB1 + 2 * 1024];
    bfv[6] = *(const short8*)&Bbuf[dB + pB0 + 3 * 1024];
    bfv[7] = *(const short8*)&Bbuf[dB + pB1 + 3 * 1024];
    ISSUE_A(ar1, n, 1);
    ISSUE_B(n, dn, 0);
    PHASE_TAIL(0);

    // ---- q1 ----
    READ_AF(1);
    ISSUE_B(n, dn, 1);
    PHASE_TAIL(1);

    // ---- q2: A(n,h0) regs ready -> cvt+write ----
    READ_AF(2);
    VMC(8);
    WRITE_A(ar0, dn, 0);
    PHASE_TAIL(2);

    // ---- q3: A(n,h1) -> cvt+write; issue A(n2,h0); retire B(n) ----
    READ_AF(3);
    VMC(4);
    WRITE_A(ar1, dn, 1);
    FENCE;
    ISSUE_A(ar0, n2, 0);
    FENCE;
    VMC(4);
    PHASE_TAIL(3);
  }

  // ---- epilogue: tanh(acc + b1q) * V, reduce over u ----
  __syncthreads();                          // drains leftover clamped staging
  const int b_blk = bm >> 3;                // 256-row tile never crosses batch
  float bqv[4], vvv[4];
#pragma unroll
  for (int nf = 0; nf < 4; ++nf) {
    const int ug = u0 + wn * 64 + nf * 16 + l15;   // D col = lane&15
    bqv[nf] = b1q[b_blk * U_ + ug];
    vvv[nf] = V[ug];
  }
  float rp[8][4];
#pragma unroll
  for (int mf = 0; mf < 8; ++mf)
#pragma unroll
    for (int j = 0; j < 4; ++j) rp[mf][j] = 0.f;
#pragma unroll
  for (int nf = 0; nf < 4; ++nf)
#pragma unroll
    for (int mf = 0; mf < 8; ++mf) {
      const f32x4 c = acc[mf][nf];
#pragma unroll
      for (int j = 0; j < 4; ++j) {
        const float x = c[j] + bqv[nf];
        const float e = __expf(2.f * x);    // inf-safe tanh
        const float tt = 1.f - 2.f / (e + 1.f);
        rp[mf][j] += tt * vvv[nf];
      }
    }
#pragma unroll
  for (int mf = 0; mf < 8; ++mf)
#pragma unroll
    for (int j = 0; j < 4; ++j) {
      float v = rp[mf][j];
      v += __shfl_xor(v, 1);
      v += __shfl_xor(v, 2);
      v += __shfl_xor(v, 4);
      v += __shfl_xor(v, 8);
      rp[mf][j] = v;
    }
  if (l15 == 0) {
#pragma unroll
    for (int mf = 0; mf < 8; ++mf)
#pragma unroll
      for (int j = 0; j < 4; ++j)
        scorebuf[(wm * 128 + mf * 16 + l16 * 4 + j) * 4 + wn] = rp[mf][j];
  }
  __syncthreads();
  if (tid < BMT) {
    const float s = scorebuf[tid * 4 + 0] + scorebuf[tid * 4 + 1] +
                    scorebuf[tid * 4 + 2] + scorebuf[tid * 4 + 3];
    score_part[(size_t)bn * (B_ * S_) + bm * BMT + tid] = s;
  }
}

// ---------- softmax over S per batch (4 u-partials; bV shift-invariant -> dropped) ----------
__global__ void k_softmax(const float* __restrict__ sp, float* __restrict__ aw) {
  __shared__ float red[8];
  const int b = blockIdx.x, tid = threadIdx.x;   // 256 threads, 8 elems each
  const int BS = B_ * S_;
  float x[8];
  float m = -1e30f;
#pragma unroll
  for (int i = 0; i < 8; ++i) {
    const int s = b * S_ + tid + i * 256;
    x[i] = sp[s] + sp[BS + s] + sp[2 * BS + s] + sp[3 * BS + s];
    m = fmaxf(m, x[i]);
  }
#pragma unroll
  for (int off = 32; off; off >>= 1) m = fmaxf(m, __shfl_xor(m, off));
  if ((tid & 63) == 0) red[tid >> 6] = m;
  __syncthreads();
  m = fmaxf(fmaxf(red[0], red[1]), fmaxf(red[2], red[3]));
  float e[8];
  float sum = 0.f;
#pragma unroll
  for (int i = 0; i < 8; ++i) { e[i] = __expf(x[i] - m); sum += e[i]; }
#pragma unroll
  for (int off = 32; off; off >>= 1) sum += __shfl_xor(sum, off);
  __syncthreads();
  if ((tid & 63) == 0) red[4 + (tid >> 6)] = sum;
  __syncthreads();
  sum = red[4] + red[5] + red[6] + red[7];
  const float inv = 1.f / sum;
#pragma unroll
  for (int i = 0; i < 8; ++i) aw[b * S_ + tid + i * 256] = e[i] * inv;
}

// ---------- context: partial weighted sums over s-chunks, then combine ----------
__global__ void k_ctx_partial(const float* __restrict__ values, const float* __restrict__ aw,
                              float* __restrict__ part) {
  __shared__ float a_s[128];
  const int b = blockIdx.y, sc = blockIdx.x, tid = threadIdx.x;  // 16 chunks x 128 s
  if (tid < 128) a_s[tid] = aw[b * S_ + sc * 128 + tid];
  __syncthreads();
  const float4* vp = (const float4*)values + (size_t)(b * S_ + sc * 128) * (H_ / 4) + tid;
  float4 acc = {0.f, 0.f, 0.f, 0.f};
#pragma unroll 4
  for (int i = 0; i < 128; ++i) {
    const float4 v = vp[(size_t)i * (H_ / 4)];
    const float a = a_s[i];
    acc.x += a * v.x; acc.y += a * v.y; acc.z += a * v.z; acc.w += a * v.w;
  }
  ((float4*)part)[(size_t)(b * 16 + sc) * (H_ / 4) + tid] = acc;
}

__global__ void k_ctx_combine(const float* __restrict__ part, float* __restrict__ ctx) {
  const int b = blockIdx.x, tid = threadIdx.x;
  float4 s = {0.f, 0.f, 0.f, 0.f};
#pragma unroll
  for (int c = 0; c < 16; ++c) {
    const float4 v = ((const float4*)part)[(size_t)(b * 16 + c) * (H_ / 4) + tid];
    s.x += v.x; s.y += v.y; s.z += v.z; s.w += v.w;
  }
  ((float4*)ctx)[b * (H_ / 4) + tid] = s;
}

extern "C" void kernel_launch(void* const* d_in, const int* in_sizes, int n_in,
                              void* d_out, int out_size, void* d_ws, size_t ws_size,
                              hipStream_t stream) {
  const float* query  = (const float*)d_in[0];
  const float* values = (const float*)d_in[1];
  const float* W1     = (const float*)d_in[2];
  const float* b1     = (const float*)d_in[3];
  const float* W2     = (const float*)d_in[4];
  const float* b2     = (const float*)d_in[5];
  const float* V      = (const float*)d_in[6];
  // d_in[7] = bV: softmax shift-invariant, affects neither output -> unused.

  char* ws = (char*)d_ws;
  unsigned short* W1T = (unsigned short*)ws;                                   // 2 MB  [U][H] bf16
  float* b1q   = (float*)(ws + 2u * 1024u * 1024u);                            // 128 KB [B][U]
  float* spart = (float*)(ws + 2u * 1024u * 1024u + 128u * 1024u);             // 1 MB  [4][B*S]
  float* cpart = (float*)(ws + 2u * 1024u * 1024u + 128u * 1024u + 1024u * 1024u); // 2 MB [B*16][H]

  float* aw  = (float*)d_out;        // [B,S,1]
  float* ctx = aw + B_ * S_;         // [B,H]

  hipLaunchKernelGGL(k_transpose_w1, dim3(16, 16), dim3(64, 4), 0, stream, W1, W1T);
  hipLaunchKernelGGL(k_b1q,          dim3(4, 32),  dim3(256),   0, stream, query, W2, b1, b2, b1q);
  hipLaunchKernelGGL(k_fused_score,  dim3(1024),   dim3(512),   0, stream, values, W1T, b1q, V, spart);
  hipLaunchKernelGGL(k_softmax,      dim3(32),     dim3(256),   0, stream, spart, aw);
  hipLaunchKernelGGL(k_ctx_partial,  dim3(16, 32), dim3(256),   0, stream, values, aw, cpart);
  hipLaunchKernelGGL(k_ctx_combine,  dim3(32),     dim3(256),   0, stream, cpart, ctx);
}

// Round 5
// 333.253 us; speedup vs baseline: 1.0314x; 1.0314x over previous
//
#include <hip/hip_runtime.h>
#include <hip/hip_bf16.h>
#include <stdint.h>

#define B_ 32
#define S_ 2048
#define H_ 1024
#define U_ 1024

typedef __attribute__((ext_vector_type(8))) short short8;
typedef __attribute__((ext_vector_type(4))) float f32x4;

#define AS1 __attribute__((address_space(1)))
#define AS3 __attribute__((address_space(3)))
#define FENCE __builtin_amdgcn_sched_barrier(0)
#define VMC(n) asm volatile("s_waitcnt vmcnt(" #n ")" ::: "memory")
#define LGKM0 asm volatile("s_waitcnt lgkmcnt(0)" ::: "memory")

__device__ __forceinline__ unsigned short f2bf(float f) {
  unsigned int u = __float_as_uint(f);
  u += 0x7fffu + ((u >> 16) & 1u);   // RNE
  return (unsigned short)(u >> 16);
}

// ---------- prep 0: values f32 -> bf16 copy ----------
__global__ void k_cvt(const float* __restrict__ v, unsigned short* __restrict__ o) {
  const size_t n = (size_t)B_ * S_ * H_;
  const size_t stride = (size_t)gridDim.x * blockDim.x * 8;
  for (size_t i = ((size_t)blockIdx.x * blockDim.x + threadIdx.x) * 8; i < n; i += stride) {
    float4 a = *(const float4*)(v + i), b = *(const float4*)(v + i + 4);
    short8 w;
    w[0]=f2bf(a.x); w[1]=f2bf(a.y); w[2]=f2bf(a.z); w[3]=f2bf(a.w);
    w[4]=f2bf(b.x); w[5]=f2bf(b.y); w[6]=f2bf(b.z); w[7]=f2bf(b.w);
    *(short8*)(o + i) = w;
  }
}

// ---------- prep 1: W1 [H][U] f32 -> W1T [U][H] bf16 ----------
__global__ void k_transpose_w1(const float* __restrict__ W1, unsigned short* __restrict__ W1T) {
  __shared__ float tile[64][65];
  const int tx = threadIdx.x, ty = threadIdx.y;
  const int u0 = blockIdx.x * 64, h0 = blockIdx.y * 64;
#pragma unroll
  for (int i = 0; i < 16; ++i) {
    int hl = ty + i * 4;
    tile[hl][tx] = W1[(size_t)(h0 + hl) * U_ + (u0 + tx)];
  }
  __syncthreads();
#pragma unroll
  for (int i = 0; i < 16; ++i) {
    int ul = ty + i * 4;
    W1T[(size_t)(u0 + ul) * H_ + (h0 + tx)] = f2bf(tile[tx][ul]);
  }
}

// ---------- prep 2: b1q[b][u] = b1[u] + b2[u] + query[b]@W2 ----------
__global__ void k_b1q(const float* __restrict__ query, const float* __restrict__ W2,
                      const float* __restrict__ b1, const float* __restrict__ b2,
                      float* __restrict__ b1q) {
  const int b = blockIdx.y;
  const int u = blockIdx.x * 256 + threadIdx.x;
  float acc = b1[u] + b2[u];
  const float* q = query + b * H_;
#pragma unroll 8
  for (int h = 0; h < H_; ++h) acc += q[h] * W2[(size_t)h * U_ + u];
  b1q[b * U_ + u] = acc;
}

// ---------- fused GEMM+tanh+V: 256x256x64, 8 waves, 4 balanced phases/K-tile ----------
#define BMT 256
#define BNT 256
#define NTILE 16   // H_/64

// LDS 128 KB: Abuf 2x[256r][64c] bf16, Bbuf same. Chunk swizzle: phys = logical ^ (row&7)
// (16B chunks; involution; 0 bank conflicts verified r2-r4).
// Phase (q = kk*2 + mhalf): reads af[mhalf*4..+4][kk] (4) (+bv[*][kk] (4) at q0/q2),
// stages exactly one half-tile (2 gl_lds/thread), 16 MFMA. One vmcnt(2)/tile, never 0.
// Rotation (CVT): t-1q3post: Bh0(t+1) | t q0: Ah0(t+1) | q1: Ah1(t+1) | q2: Bh1(t+1)
// | q3post: Bh0(t+2), VMC(2).  All writes land in buffers whose readers drained
// (per-wave LGKM0/VMC before a common barrier).
template<bool CVT>
__global__ __launch_bounds__(512, 2)
void k_fused_score(const float* __restrict__ valsf, const unsigned short* __restrict__ vbf,
                   const unsigned short* __restrict__ W1T, const float* __restrict__ b1q,
                   const float* __restrict__ V, float* __restrict__ score_part) {
  __shared__ __align__(16) unsigned char smem[131072];
  unsigned short* Abuf = (unsigned short*)smem;              // [2][256*64]
  unsigned short* Bbuf = (unsigned short*)(smem + 65536);    // [2][256*64]
  float* scorebuf = (float*)smem;                            // alias post-loop

  const int tid = threadIdx.x;
  const int g = blockIdx.x;                 // 1024 = 256 bm x 4 bn
  const int seq = (g & 7) * 128 + (g >> 3); // XCD swizzle (bijective)
  const int bn = seq & 3;
  const int bm = seq >> 2;

  const int lane = tid & 63, wid = tid >> 6;
  const int wm = wid >> 2, wn = wid & 3;
  const int u0 = bn * BNT;

  const int l15 = lane & 15, l16 = lane >> 4, l7 = lane & 7;
  const int pA0 = (wm * 128 + l15) * 64 + ((0 + l16) ^ l7) * 8;   // kk=0
  const int pA1 = (wm * 128 + l15) * 64 + ((4 + l16) ^ l7) * 8;   // kk=1
  const int pB0 = (wn * 64 + l15) * 64 + ((0 + l16) ^ l7) * 8;
  const int pB1 = (wn * 64 + l15) * 64 + ((4 + l16) ^ l7) * 8;

  const int lcs = (lane & 7) ^ ((lane >> 3) & 7);   // pre-swizzled source chunk
  // f32 reg-staging path (CVT=false)
  const int arow = tid >> 2, acp = (tid & 3) * 2;

  f32x4 acc[8][4];
#pragma unroll
  for (int mf = 0; mf < 8; ++mf)
#pragma unroll
    for (int nf = 0; nf < 4; ++nf) acc[mf][nf] = (f32x4){0.f, 0.f, 0.f, 0.f};

  float4 ar0[4], ar1[4];
  short8 af_[4], bv[4];

#define STAGE_A(tt, dd, h) { \
    _Pragma("unroll") \
    for (int j_ = 0; j_ < 2; ++j_) { \
      const int p_ = (h) * 1024 + (wid * 2 + j_) * 64 + lane; \
      const int nr_ = p_ >> 3; \
      const unsigned short* s_ = vbf + (size_t)(bm * BMT + nr_) * H_ + (tt) * 64 + lcs * 8; \
      __builtin_amdgcn_global_load_lds((const AS1 void*)s_, (AS3 void*)&Abuf[(dd) * 16384 + p_ * 8], 16, 0, 0); } }

#define STAGE_B(tt, dd, h) { \
    _Pragma("unroll") \
    for (int j_ = 0; j_ < 2; ++j_) { \
      const int p_ = (h) * 1024 + (wid * 2 + j_) * 64 + lane; \
      const int nr_ = p_ >> 3; \
      const unsigned short* s_ = W1T + (size_t)(u0 + nr_) * H_ + (tt) * 64 + lcs * 8; \
      __builtin_amdgcn_global_load_lds((const AS1 void*)s_, (AS3 void*)&Bbuf[(dd) * 16384 + p_ * 8], 16, 0, 0); } }

#define ISSUE_AR(reg, tt, h) { \
    const float4* ap_ = (const float4*)(valsf + (size_t)(bm * BMT + (h) * 128 + arow) * H_ + (tt) * 64 + acp * 8); \
    reg[0] = ap_[0]; reg[1] = ap_[1]; reg[2] = ap_[2]; reg[3] = ap_[3]; }

#define WRITE_AR(reg, dd, h) { \
    short8 w0_, w1_; \
    w0_[0]=f2bf(reg[0].x); w0_[1]=f2bf(reg[0].y); w0_[2]=f2bf(reg[0].z); w0_[3]=f2bf(reg[0].w); \
    w0_[4]=f2bf(reg[1].x); w0_[5]=f2bf(reg[1].y); w0_[6]=f2bf(reg[1].z); w0_[7]=f2bf(reg[1].w); \
    w1_[0]=f2bf(reg[2].x); w1_[1]=f2bf(reg[2].y); w1_[2]=f2bf(reg[2].z); w1_[3]=f2bf(reg[2].w); \
    w1_[4]=f2bf(reg[3].x); w1_[5]=f2bf(reg[3].y); w1_[6]=f2bf(reg[3].z); w1_[7]=f2bf(reg[3].w); \
    const int rl_ = (h) * 128 + arow; \
    *(short8*)&Abuf[(dd) * 16384 + rl_ * 64 + ((acp ^ (rl_ & 7)) << 3)] = w0_; \
    *(short8*)&Abuf[(dd) * 16384 + rl_ * 64 + (((acp + 1) ^ (rl_ & 7)) << 3)] = w1_; }

#define READ_AF(PA, MH) \
    af_[0] = *(const short8*)&Abuf[dA + (PA) + ((MH) * 4 + 0) * 1024]; \
    af_[1] = *(const short8*)&Abuf[dA + (PA) + ((MH) * 4 + 1) * 1024]; \
    af_[2] = *(const short8*)&Abuf[dA + (PA) + ((MH) * 4 + 2) * 1024]; \
    af_[3] = *(const short8*)&Abuf[dA + (PA) + ((MH) * 4 + 3) * 1024];

#define READ_BV(PB) \
    bv[0] = *(const short8*)&Bbuf[dB + (PB)]; \
    bv[1] = *(const short8*)&Bbuf[dB + (PB) + 1024]; \
    bv[2] = *(const short8*)&Bbuf[dB + (PB) + 2048]; \
    bv[3] = *(const short8*)&Bbuf[dB + (PB) + 3072];

#define MFMA16(MH) \
    _Pragma("unroll") \
    for (int nf_ = 0; nf_ < 4; ++nf_) { \
      acc[(MH)*4+0][nf_] = __builtin_amdgcn_mfma_f32_16x16x32_bf16(af_[0], bv[nf_], acc[(MH)*4+0][nf_], 0, 0, 0); \
      acc[(MH)*4+1][nf_] = __builtin_amdgcn_mfma_f32_16x16x32_bf16(af_[1], bv[nf_], acc[(MH)*4+1][nf_], 0, 0, 0); \
      acc[(MH)*4+2][nf_] = __builtin_amdgcn_mfma_f32_16x16x32_bf16(af_[2], bv[nf_], acc[(MH)*4+2][nf_], 0, 0, 0); \
      acc[(MH)*4+3][nf_] = __builtin_amdgcn_mfma_f32_16x16x32_bf16(af_[3], bv[nf_], acc[(MH)*4+3][nf_], 0, 0, 0); \
    }

#define PH_HEAD FENCE; __builtin_amdgcn_s_barrier(); LGKM0; FENCE; __builtin_amdgcn_s_setprio(1)
#define PH_MID  __builtin_amdgcn_s_setprio(0)
#define PH_END  FENCE; __builtin_amdgcn_s_barrier()

  // ---- prologue: tile 0 fully staged ----
  if constexpr (CVT) {
    STAGE_A(0, 0, 0); STAGE_A(0, 0, 1);
    STAGE_B(0, 0, 0); STAGE_B(0, 0, 1);
    VMC(0);
    __builtin_amdgcn_s_barrier();
    STAGE_B(1, 1, 0);                        // keeper: Bh0(1), in flight
  } else {
    ISSUE_AR(ar0, 0, 0); ISSUE_AR(ar1, 0, 1);
    STAGE_B(0, 0, 0); STAGE_B(0, 0, 1);
    VMC(8);  WRITE_AR(ar0, 0, 0);
    VMC(4);  WRITE_AR(ar1, 0, 1);
    FENCE;
    ISSUE_AR(ar0, 1, 0); ISSUE_AR(ar1, 1, 1); // tile1 A -> regs, in flight
    FENCE;
    VMC(8);                                  // B(0) landed
    LGKM0;
    __builtin_amdgcn_s_barrier();
  }

  for (int t = 0; t < NTILE; ++t) {
    const int d = t & 1, dn = d ^ 1;
    const int dA = d * 16384, dB = d * 16384;
    const int n  = (t + 1 < NTILE) ? t + 1 : NTILE - 1;
    const int n2 = (t + 2 < NTILE) ? t + 2 : NTILE - 1;

    // ---- q0: kk=0, mf 0-3 ----
    READ_BV(pB0);
    READ_AF(pA0, 0);
    if constexpr (CVT) { STAGE_A(n, dn, 0); } else { STAGE_B(n, dn, 0); }
    PH_HEAD; MFMA16(0); PH_MID; PH_END;

    // ---- q1: kk=0, mf 4-7 ----
    READ_AF(pA0, 1);
    if constexpr (CVT) { STAGE_A(n, dn, 1); } else { STAGE_B(n, dn, 1); }
    PH_HEAD; MFMA16(1); PH_MID; PH_END;

    // ---- q2: kk=1, mf 0-3 ----
    READ_BV(pB1);
    READ_AF(pA1, 0);
    if constexpr (CVT) { STAGE_B(n, dn, 1); }
    else { VMC(8); WRITE_AR(ar0, dn, 0); }
    PH_HEAD; MFMA16(0); PH_MID; PH_END;

    // ---- q3: kk=1, mf 4-7; keeper + single counted wait per tile ----
    READ_AF(pA1, 1);
    if constexpr (!CVT) { VMC(4); WRITE_AR(ar1, dn, 1); }
    PH_HEAD; MFMA16(1); PH_MID;
    if constexpr (CVT) {
      STAGE_B(n2, d, 0);                     // keeper: Bh0(t+2)
      VMC(2);                                // retire everything for tile t+1
    } else {
      FENCE;
      ISSUE_AR(ar0, n2, 0); ISSUE_AR(ar1, n2, 1);  // keepers: A(t+2) -> regs
      FENCE;
      VMC(8);                                // retire B(t+1)
    }
    PH_END;
  }

  // ---- epilogue: tanh(acc + b1q) * V, reduce over u ----
  __syncthreads();                           // drains keeper loads
  const int b_blk = bm >> 3;                 // 256-row tile never crosses batch
  float bqv[4], vvv[4];
#pragma unroll
  for (int nf = 0; nf < 4; ++nf) {
    const int ug = u0 + wn * 64 + nf * 16 + l15;   // D col = lane&15
    bqv[nf] = b1q[b_blk * U_ + ug];
    vvv[nf] = V[ug];
  }
  float rp[8][4];
#pragma unroll
  for (int mf = 0; mf < 8; ++mf)
#pragma unroll
    for (int j = 0; j < 4; ++j) rp[mf][j] = 0.f;
#pragma unroll
  for (int nf = 0; nf < 4; ++nf)
#pragma unroll
    for (int mf = 0; mf < 8; ++mf) {
      const f32x4 c = acc[mf][nf];
#pragma unroll
      for (int j = 0; j < 4; ++j) {
        const float x = c[j] + bqv[nf];
        const float e = __expf(2.f * x);     // inf-safe tanh
        const float tt = 1.f - 2.f / (e + 1.f);
        rp[mf][j] += tt * vvv[nf];
      }
    }
#pragma unroll
  for (int mf = 0; mf < 8; ++mf)
#pragma unroll
    for (int j = 0; j < 4; ++j) {
      float v = rp[mf][j];
      v += __shfl_xor(v, 1);
      v += __shfl_xor(v, 2);
      v += __shfl_xor(v, 4);
      v += __shfl_xor(v, 8);
      rp[mf][j] = v;
    }
  if (l15 == 0) {
#pragma unroll
    for (int mf = 0; mf < 8; ++mf)
#pragma unroll
      for (int j = 0; j < 4; ++j)
        scorebuf[(wm * 128 + mf * 16 + l16 * 4 + j) * 4 + wn] = rp[mf][j];
  }
  __syncthreads();
  if (tid < BMT) {
    const float s = scorebuf[tid * 4 + 0] + scorebuf[tid * 4 + 1] +
                    scorebuf[tid * 4 + 2] + scorebuf[tid * 4 + 3];
    score_part[(size_t)bn * (B_ * S_) + bm * BMT + tid] = s;
  }
}

// ---------- softmax over S per batch (4 u-partials; bV shift-invariant -> dropped) ----------
__global__ void k_softmax(const float* __restrict__ sp, float* __restrict__ aw) {
  __shared__ float red[8];
  const int b = blockIdx.x, tid = threadIdx.x;   // 256 threads, 8 elems each
  const int BS = B_ * S_;
  float x[8];
  float m = -1e30f;
#pragma unroll
  for (int i = 0; i < 8; ++i) {
    const int s = b * S_ + tid + i * 256;
    x[i] = sp[s] + sp[BS + s] + sp[2 * BS + s] + sp[3 * BS + s];
    m = fmaxf(m, x[i]);
  }
#pragma unroll
  for (int off = 32; off; off >>= 1) m = fmaxf(m, __shfl_xor(m, off));
  if ((tid & 63) == 0) red[tid >> 6] = m;
  __syncthreads();
  m = fmaxf(fmaxf(red[0], red[1]), fmaxf(red[2], red[3]));
  float e[8];
  float sum = 0.f;
#pragma unroll
  for (int i = 0; i < 8; ++i) { e[i] = __expf(x[i] - m); sum += e[i]; }
#pragma unroll
  for (int off = 32; off; off >>= 1) sum += __shfl_xor(sum, off);
  __syncthreads();
  if ((tid & 63) == 0) red[4 + (tid >> 6)] = sum;
  __syncthreads();
  sum = red[4] + red[5] + red[6] + red[7];
  const float inv = 1.f / sum;
#pragma unroll
  for (int i = 0; i < 8; ++i) aw[b * S_ + tid + i * 256] = e[i] * inv;
}

// ---------- context: partial weighted sums over s-chunks, then combine ----------
__global__ void k_ctx_partial(const float* __restrict__ values, const float* __restrict__ aw,
                              float* __restrict__ part) {
  __shared__ float a_s[128];
  const int b = blockIdx.y, sc = blockIdx.x, tid = threadIdx.x;  // 16 chunks x 128 s
  if (tid < 128) a_s[tid] = aw[b * S_ + sc * 128 + tid];
  __syncthreads();
  const float4* vp = (const float4*)values + (size_t)(b * S_ + sc * 128) * (H_ / 4) + tid;
  float4 acc = {0.f, 0.f, 0.f, 0.f};
#pragma unroll 4
  for (int i = 0; i < 128; ++i) {
    const float4 v = vp[(size_t)i * (H_ / 4)];
    const float a = a_s[i];
    acc.x += a * v.x; acc.y += a * v.y; acc.z += a * v.z; acc.w += a * v.w;
  }
  ((float4*)part)[(size_t)(b * 16 + sc) * (H_ / 4) + tid] = acc;
}

__global__ void k_ctx_combine(const float* __restrict__ part, float* __restrict__ ctx) {
  const int b = blockIdx.x, tid = threadIdx.x;
  float4 s = {0.f, 0.f, 0.f, 0.f};
#pragma unroll
  for (int c = 0; c < 16; ++c) {
    const float4 v = ((const float4*)part)[(size_t)(b * 16 + c) * (H_ / 4) + tid];
    s.x += v.x; s.y += v.y; s.z += v.z; s.w += v.w;
  }
  ((float4*)ctx)[b * (H_ / 4) + tid] = s;
}

extern "C" void kernel_launch(void* const* d_in, const int* in_sizes, int n_in,
                              void* d_out, int out_size, void* d_ws, size_t ws_size,
                              hipStream_t stream) {
  const float* query  = (const float*)d_in[0];
  const float* values = (const float*)d_in[1];
  const float* W1     = (const float*)d_in[2];
  const float* b1     = (const float*)d_in[3];
  const float* W2     = (const float*)d_in[4];
  const float* b2     = (const float*)d_in[5];
  const float* V      = (const float*)d_in[6];
  // d_in[7] = bV: softmax shift-invariant, affects neither output -> unused.

  char* ws = (char*)d_ws;
  unsigned short* W1T = (unsigned short*)ws;                                   // 2 MB  [U][H] bf16
  float* b1q   = (float*)(ws + 2u * 1024u * 1024u);                            // 128 KB [B][U]
  float* spart = (float*)(ws + 2u * 1024u * 1024u + 128u * 1024u);             // 1 MB  [4][B*S]
  float* cpart = (float*)(ws + 2u * 1024u * 1024u + 128u * 1024u + 1024u * 1024u); // 2 MB
  unsigned short* vbf = (unsigned short*)(ws + 8u * 1024u * 1024u);            // 128 MB [B*S][H] bf16
  const bool useCvt = ws_size >= (size_t)136 * 1024 * 1024;

  float* aw  = (float*)d_out;        // [B,S,1]
  float* ctx = aw + B_ * S_;         // [B,H]

  k_transpose_w1<<<dim3(16, 16), dim3(64, 4), 0, stream>>>(W1, W1T);
  k_b1q<<<dim3(4, 32), dim3(256), 0, stream>>>(query, W2, b1, b2, b1q);
  if (useCvt) {
    k_cvt<<<dim3(2048), dim3(256), 0, stream>>>(values, vbf);
    k_fused_score<true><<<dim3(1024), dim3(512), 0, stream>>>(values, vbf, W1T, b1q, V, spart);
  } else {
    k_fused_score<false><<<dim3(1024), dim3(512), 0, stream>>>(values, vbf, W1T, b1q, V, spart);
  }
  k_softmax<<<dim3(32), dim3(256), 0, stream>>>(spart, aw);
  k_ctx_partial<<<dim3(16, 32), dim3(256), 0, stream>>>(values, aw, cpart);
  k_ctx_combine<<<dim3(32), dim3(256), 0, stream>>>(cpart, ctx);
}